// Round 1
// baseline (377.198 us; speedup 1.0000x reference)
//
#include <hip/hip_runtime.h>
#include <math.h>

#define NN 4096
#define MM 64
#define THREADS 1024

__device__ __forceinline__ float wave_red_sum(float v) {
#pragma unroll
    for (int o = 32; o > 0; o >>= 1) v += __shfl_down(v, o, 64);
    return v;
}
__device__ __forceinline__ float wave_red_max(float v) {
#pragma unroll
    for (int o = 32; o > 0; o >>= 1) v = fmaxf(v, __shfl_down(v, o, 64));
    return v;
}

// Block-wide reductions over 1024 threads (16 waves). scratch needs >= 17 floats.
__device__ __forceinline__ float block_sum(float v, float* scratch) {
    const int tid = threadIdx.x;
    const int lane = tid & 63, wid = tid >> 6;
    v = wave_red_sum(v);
    if (lane == 0) scratch[wid] = v;
    __syncthreads();
    if (tid < 64) {
        float x = (tid < 16) ? scratch[tid] : 0.0f;
        x = wave_red_sum(x);
        if (tid == 0) scratch[16] = x;
    }
    __syncthreads();
    float r = scratch[16];
    __syncthreads();   // make scratch reusable by the next reduction
    return r;
}
__device__ __forceinline__ float block_max(float v, float* scratch) {
    const int tid = threadIdx.x;
    const int lane = tid & 63, wid = tid >> 6;
    v = wave_red_max(v);
    if (lane == 0) scratch[wid] = v;
    __syncthreads();
    if (tid < 64) {
        float x = (tid < 16) ? scratch[tid] : -INFINITY;
        x = wave_red_max(x);
        if (tid == 0) scratch[16] = x;
    }
    __syncthreads();
    float r = scratch[16];
    __syncthreads();
    return r;
}

extern "C" __global__ void __launch_bounds__(THREADS)
ntm_head_kernel(const float* __restrict__ memory, const float* __restrict__ k,
                const float* __restrict__ beta, const float* __restrict__ prev_w,
                const float* __restrict__ g, const float* __restrict__ s,
                const float* __restrict__ gamma, float* __restrict__ out) {
    __shared__ float dotA[NN];   // 16 KB
    __shared__ float sqA[NN];    // 16 KB
    __shared__ float wg[NN];     // 16 KB
    __shared__ float kk[MM];
    __shared__ float scratch[32];
    __shared__ float knorm_sh;

    const int b = blockIdx.x;
    const int tid = threadIdx.x;
    const float* __restrict__ memB = memory + (size_t)b * NN * MM;

    if (tid < MM) kk[tid] = k[b * MM + tid];
    __syncthreads();

    // k_norm (wave 0 only)
    if (tid < 64) {
        float kv2 = kk[tid] * kk[tid];
        float sk = wave_red_sum(kv2);
        if (tid == 0) knorm_sh = fmaxf(sqrtf(sk), 1e-8f);
    }

    // per-thread slice of k (fixed 4 contiguous elements, m = (tid%16)*4 .. +3)
    const int m4 = (tid & 15) * 4;
    const float kx = kk[m4], ky = kk[m4 + 1], kz = kk[m4 + 2], kw = kk[m4 + 3];

    // ---- Phase A: stream memory, compute per-row dot and squared norm ----
    // Each wave covers 4 rows per iteration; element offset = it*4096 + tid*4.
#pragma unroll 4
    for (int it = 0; it < 64; ++it) {
        const float4 mv = *(const float4*)(memB + (size_t)it * 4096 + tid * 4);
        float d = mv.x * kx + mv.y * ky + mv.z * kz + mv.w * kw;
        float q = mv.x * mv.x + mv.y * mv.y + mv.z * mv.z + mv.w * mv.w;
#pragma unroll
        for (int o = 8; o >= 1; o >>= 1) {
            d += __shfl_down(d, o, 16);
            q += __shfl_down(q, o, 16);
        }
        if ((tid & 15) == 0) {
            const int n = it * 64 + (tid >> 4);
            dotA[n] = d;
            sqA[n] = q;
        }
    }
    __syncthreads();

    const float knorm = knorm_sh;
    const float beta_b = beta[b];
    const float g_b = g[b];
    const float s0 = s[b * 3], s1 = s[b * 3 + 1], s2 = s[b * 3 + 2];
    const float gamma_b = gamma[b];

    // ---- Phase B: scaled similarity + block max ----
    float val[4];
    float lmax = -INFINITY;
#pragma unroll
    for (int j = 0; j < 4; ++j) {
        const int n = tid + j * THREADS;
        const float mn = fmaxf(sqrtf(sqA[n]), 1e-8f);
        const float v = beta_b * (dotA[n] / (knorm * mn));
        val[j] = v;
        lmax = fmaxf(lmax, v);
    }
    const float mx = block_max(lmax, scratch);

    // ---- Phase C: softmax ----
    float e[4];
    float lsum = 0.0f;
#pragma unroll
    for (int j = 0; j < 4; ++j) {
        e[j] = expf(val[j] - mx);
        lsum += e[j];
    }
    const float sumE = block_sum(lsum, scratch);

    // ---- Phase D: gated interpolation into LDS ----
#pragma unroll
    for (int j = 0; j < 4; ++j) {
        const int n = tid + j * THREADS;
        const float wc = e[j] / sumE;
        const float pw = prev_w[(size_t)b * NN + n];
        wg[n] = g_b * wc + (1.0f - g_b) * pw;
    }
    __syncthreads();

    // ---- Phase E: circular 3-tap shift, sharpen, normalize ----
    float wp[4];
    float lsum2 = 0.0f;
#pragma unroll
    for (int j = 0; j < 4; ++j) {
        const int n = tid + j * THREADS;
        const int nm = (n + NN - 1) & (NN - 1);
        const int np_ = (n + 1) & (NN - 1);
        const float ws = s0 * wg[nm] + s1 * wg[n] + s2 * wg[np_];
        const float p = (float)pow((double)ws, (double)gamma_b);
        wp[j] = p;
        lsum2 += p;
    }
    const float sumP = block_sum(lsum2, scratch);
    const float denom = sumP + 1e-16f;
#pragma unroll
    for (int j = 0; j < 4; ++j) {
        const int n = tid + j * THREADS;
        out[(size_t)b * NN + n] = wp[j] / denom;
    }
}

extern "C" void kernel_launch(void* const* d_in, const int* in_sizes, int n_in,
                              void* d_out, int out_size, void* d_ws, size_t ws_size,
                              hipStream_t stream) {
    const float* memory = (const float*)d_in[0];
    const float* k      = (const float*)d_in[1];
    const float* beta   = (const float*)d_in[2];
    const float* prev_w = (const float*)d_in[3];
    const float* g      = (const float*)d_in[4];
    const float* s      = (const float*)d_in[5];
    const float* gamma  = (const float*)d_in[6];
    float* out = (float*)d_out;

    const int B = in_sizes[2];  // beta is [B,1]
    ntm_head_kernel<<<B, THREADS, 0, stream>>>(memory, k, beta, prev_w, g, s, gamma, out);
}